// Round 18
// baseline (1445.053 us; speedup 1.0000x reference)
//
#include <hip/hip_runtime.h>
#include <hip/hip_fp16.h>

#define DD 32
#define NLAYERS 8
#define TOPK 8

typedef float f32x4 __attribute__((ext_vector_type(4)));

__device__ __forceinline__ unsigned encf(float x){ unsigned u=__float_as_uint(x); return (u&0x80000000u)? ~u : (u|0x80000000u); }
__device__ __forceinline__ unsigned short f2h(float f){ return __half_as_ushort(__float2half(f)); }
__device__ __forceinline__ float h2f(unsigned short u){ return __half2float(__ushort_as_half(u)); }
__device__ __forceinline__ float4 up4(uint2 u){
  float4 r;
  r.x=h2f((unsigned short)(u.x&0xFFFFu)); r.y=h2f((unsigned short)(u.x>>16));
  r.z=h2f((unsigned short)(u.y&0xFFFFu)); r.w=h2f((unsigned short)(u.y>>16));
  return r;
}
// pack 4 f32 -> 4 fp8 e4m3 (OCP) in one uint
__device__ __forceinline__ unsigned pk4f8(float a, float b, float c, float d){
  int r = __builtin_amdgcn_cvt_pk_fp8_f32(a, b, 0, false);
  r = __builtin_amdgcn_cvt_pk_fp8_f32(c, d, r, true);
  return (unsigned)r;
}
union U64 { uint2 u; long long l; };
__device__ __forceinline__ int gidx(const void* p, long i, int i64){
  return i64 ? (int)((const long long*)p)[i] : ((const int*)p)[i];
}

__global__ void k_detect(const int* __restrict__ srcw, int* __restrict__ iflag){
  if (threadIdx.x==0 && blockIdx.x==0){
    int allz = 1;
    for (int k=1;k<32;k+=2) if (srcw[k]!=0) allz = 0;
    *iflag = allz;
  }
}

__global__ void k_zero(int* cnt, int* cursor, int N){
  int n = blockIdx.x*blockDim.x + threadIdx.x;
  if (n<N){ cnt[n]=0; cursor[n]=0; }
}

// h16 = fp16(relu(tok_emb[h_tok])) ; in-degree histogram
__global__ void k_init(const void* __restrict__ h_tok, const void* __restrict__ dstv,
                       const float* __restrict__ tok_emb,
                       unsigned short* __restrict__ h16, int* __restrict__ cnt,
                       const int* __restrict__ iflag, int N, int E)
{
  int i64 = *iflag;
  long idx = (long)blockIdx.x*blockDim.x + threadIdx.x;
  if (idx < (long)N*8){
    int n=(int)(idx>>3), q=(int)(idx&7);
    int t = gidx(h_tok, n, i64);
    float4 v = reinterpret_cast<const float4*>(tok_emb)[t*8+q];
    uint2 o;
    o.x = (unsigned)f2h(fmaxf(v.x,0.f)) | ((unsigned)f2h(fmaxf(v.y,0.f))<<16);
    o.y = (unsigned)f2h(fmaxf(v.z,0.f)) | ((unsigned)f2h(fmaxf(v.w,0.f))<<16);
    reinterpret_cast<uint2*>(h16)[(long)n*8+q] = o;
    return;
  }
  idx -= (long)N*8;
  if (idx < E){
    atomicAdd(&cnt[gidx(dstv, idx, i64)], 1);
  }
}

// single-block exclusive scan of in-degrees -> csr_off (wave shuffle-scan)
__global__ __launch_bounds__(1024) void k_scan(const int* __restrict__ cnt, int* __restrict__ off,
                                               int N, int E){
  __shared__ int wsum[16];
  __shared__ int carry_s;
  int tid = threadIdx.x;
  int lane = tid & 63, w = tid >> 6;
  if (tid==0) carry_s = 0;
  __syncthreads();
  for (int base=0; base<N; base+=1024){
    int v = (base+tid<N)? cnt[base+tid] : 0;
    int x = v;
    #pragma unroll
    for (int d=1; d<64; d<<=1){
      int t = __shfl_up(x, d, 64);
      if (lane>=d) x += t;
    }
    if (lane==63) wsum[w] = x;
    __syncthreads();
    if (w==0 && lane<16){
      int y = wsum[lane];
      #pragma unroll
      for (int d=1; d<16; d<<=1){
        int t = __shfl_up(y, d, 64);
        if (lane>=d) y += t;
      }
      wsum[lane] = y;
    }
    __syncthreads();
    int cl = carry_s;
    int wb = (w>0)? wsum[w-1] : 0;
    int tot = wsum[15];
    if (base+tid<N) off[base+tid] = cl + x + wb - v;
    __syncthreads();
    if (tid==0) carry_s = cl + tot;
    __syncthreads();
  }
  if (tid==0) off[N] = E;
}

// CSR positions: ONE 8-B scatter per edge (sd + edge id in a single uint2)
__global__ void k_scatter(const void* __restrict__ srcv, const void* __restrict__ dstv,
                          const int* __restrict__ off, int* __restrict__ cursor,
                          uint2* __restrict__ sde8,
                          const int* __restrict__ iflag, int E){
  int i64 = *iflag;
  int e = blockIdx.x*blockDim.x + threadIdx.x;
  if (e>=E) return;
  int d = gidx(dstv, e, i64), s = gidx(srcv, e, i64);
  int pos = off[d] + atomicAdd(&cursor[d],1);
  uint2 r; r.x = ((unsigned)d<<16) | (unsigned)s; r.y = (unsigned)e;
  sde8[pos] = r;
}

// stream sde8: emit csr_sd sequentially + fill ebuf (fp8) from L1-resident e_emb table
__global__ void k_fill(const uint2* __restrict__ sde8, const void* __restrict__ e_tok,
                       const float* __restrict__ e_emb,
                       unsigned* __restrict__ csr_sd, unsigned char* __restrict__ ebuf,
                       const int* __restrict__ iflag, int E){
  int i64 = *iflag;
  long idx = (long)blockIdx.x*blockDim.x + threadIdx.x;
  if (idx >= (long)E*2) return;
  int pos = (int)(idx>>1), j = (int)(idx&1);
  uint2 r = sde8[pos];
  if (j==0) csr_sd[pos] = r.x;
  int t = gidx(e_tok, (int)r.y, i64);
  const float4* sp = reinterpret_cast<const float4*>(e_emb + t*DD) + j*4;
  float4 x0 = sp[0], x1 = sp[1], x2 = sp[2], x3 = sp[3];
  uint4 ov;
  ov.x = pk4f8(x0.x,x0.y,x0.z,x0.w);
  ov.y = pk4f8(x1.x,x1.y,x1.z,x1.w);
  ov.z = pk4f8(x2.x,x2.y,x2.z,x2.w);
  ov.w = pk4f8(x3.x,x3.y,x3.z,x3.w);
  reinterpret_cast<uint4*>(ebuf)[(long)pos*2+j] = ov;
}

// hA16=h16@Wni, hB16=h16@Wnj   (first layer only)
__global__ __launch_bounds__(256) void k_nodeAB(
    const unsigned short* __restrict__ h16,
    const float* __restrict__ WA, const float* __restrict__ WB,
    unsigned short* __restrict__ hA16, unsigned short* __restrict__ hB16, int N)
{
  __shared__ float hl[8][DD];
  int tid = threadIdx.x;
  int ln = tid>>5, c = tid&31;
  int n = blockIdx.x*8 + ln;
  hl[ln][c] = (n<N)? h2f(h16[(long)n*DD+c]) : 0.f;
  __syncthreads();
  float a=0.f,b=0.f;
  #pragma unroll
  for (int k=0;k<DD;k++){
    float v = hl[ln][k];
    a = fmaf(v, WA[k*DD+c], a);
    b = fmaf(v, WB[k*DD+c], b);
  }
  if (n<N){ hA16[(long)n*DD+c]=f2h(a); hB16[(long)n*DD+c]=f2h(b); }
}

// MFMA fp8 edge kernel, SOFTWARE-PIPELINED (depth 1): one wave = 16 edges.
// D[m][n=edge]=Wf^T·e^T (fp8×fp8→f32); f=leaky(D+hA[src]+hB[dst]+b); ebuf<-fp8(f);
// lbuf=exp(f·attn)
__global__ __launch_bounds__(256) void k_edge(
    unsigned char* __restrict__ ebuf,
    const unsigned short* __restrict__ hA16, const unsigned short* __restrict__ hB16,
    const unsigned* __restrict__ csr_sd,
    const float* __restrict__ Wf, const float* __restrict__ bvec,
    const float* __restrict__ attn,
    unsigned short* __restrict__ lbuf, int ntiles, int writef)
{
  int lane = threadIdx.x & 63;
  int wid = (blockIdx.x*256 + threadIdx.x) >> 6;
  int nw  = (gridDim.x*256) >> 6;
  int m = lane & 15, q = lane >> 4;
  // A fragments (fp8): A[m=out_chan][k=q*8+j] = Wf[k][m], two out-chan halves
  U64 a0, a1;
  a0.u.x = pk4f8(Wf[(q*8+0)*DD+m], Wf[(q*8+1)*DD+m], Wf[(q*8+2)*DD+m], Wf[(q*8+3)*DD+m]);
  a0.u.y = pk4f8(Wf[(q*8+4)*DD+m], Wf[(q*8+5)*DD+m], Wf[(q*8+6)*DD+m], Wf[(q*8+7)*DD+m]);
  a1.u.x = pk4f8(Wf[(q*8+0)*DD+16+m], Wf[(q*8+1)*DD+16+m], Wf[(q*8+2)*DD+16+m], Wf[(q*8+3)*DD+16+m]);
  a1.u.y = pk4f8(Wf[(q*8+4)*DD+16+m], Wf[(q*8+5)*DD+16+m], Wf[(q*8+6)*DD+16+m], Wf[(q*8+7)*DD+16+m]);
  float4 blo = *reinterpret_cast<const float4*>(bvec + q*4);
  float4 bhi = *reinterpret_cast<const float4*>(bvec + 16 + q*4);
  float4 alo = *reinterpret_cast<const float4*>(attn + q*4);
  float4 ahi = *reinterpret_cast<const float4*>(attn + 16 + q*4);
  f32x4 zero = {0.f,0.f,0.f,0.f};
  // pipeline preamble: load tile wid fully
  U64 b_c; b_c.l = 0;
  unsigned sd_c = 0;
  uint2 uA0_c={0,0}, uA1_c={0,0}, uB0_c={0,0}, uB1_c={0,0};
  if (wid < ntiles){
    long e0 = (long)wid*16 + m;
    sd_c = csr_sd[e0];
    b_c.u = *reinterpret_cast<const uint2*>(ebuf + e0*DD + q*8);
    unsigned s = sd_c & 0xFFFFu, d = sd_c >> 16;
    const uint2* pA = reinterpret_cast<const uint2*>(hA16 + (long)s*DD);
    const uint2* pB = reinterpret_cast<const uint2*>(hB16 + (long)d*DD);
    uA0_c=pA[q]; uA1_c=pA[4+q]; uB0_c=pB[q]; uB1_c=pB[4+q];
  }
  for (int t = wid; t < ntiles; t += nw){
    int tn = t + nw;
    // 1) issue next tile's sd + b
    unsigned sd_n = 0; U64 b_n; b_n.l = 0;
    if (tn < ntiles){
      long en = (long)tn*16 + m;
      sd_n = csr_sd[en];
      b_n.u = *reinterpret_cast<const uint2*>(ebuf + en*DD + q*8);
    }
    // 2) MFMA on current tile
    f32x4 d0 = __builtin_amdgcn_mfma_f32_16x16x32_fp8_fp8(a0.l, b_c.l, zero, 0,0,0);
    f32x4 d1 = __builtin_amdgcn_mfma_f32_16x16x32_fp8_fp8(a1.l, b_c.l, zero, 0,0,0);
    // 3) issue next tile's gathers
    uint2 uA0_n={0,0}, uA1_n={0,0}, uB0_n={0,0}, uB1_n={0,0};
    if (tn < ntiles){
      unsigned s = sd_n & 0xFFFFu, d = sd_n >> 16;
      const uint2* pA = reinterpret_cast<const uint2*>(hA16 + (long)s*DD);
      const uint2* pB = reinterpret_cast<const uint2*>(hB16 + (long)d*DD);
      uA0_n=pA[q]; uA1_n=pA[4+q]; uB0_n=pB[q]; uB1_n=pB[4+q];
    }
    // 4) epilogue (fp32 math)
    long tbase = (long)t*16;
    long edge = tbase + m;
    float4 A0 = up4(uA0_c), A1 = up4(uA1_c);
    float4 B0 = up4(uB0_c), B1 = up4(uB1_c);
    float f00 = d0[0]+A0.x+B0.x+blo.x, f01 = d0[1]+A0.y+B0.y+blo.y;
    float f02 = d0[2]+A0.z+B0.z+blo.z, f03 = d0[3]+A0.w+B0.w+blo.w;
    float f10 = d1[0]+A1.x+B1.x+bhi.x, f11 = d1[1]+A1.y+B1.y+bhi.y;
    float f12 = d1[2]+A1.z+B1.z+bhi.z, f13 = d1[3]+A1.w+B1.w+bhi.w;
    f00 = (f00>0.f)?f00:0.01f*f00; f01 = (f01>0.f)?f01:0.01f*f01;
    f02 = (f02>0.f)?f02:0.01f*f02; f03 = (f03>0.f)?f03:0.01f*f03;
    f10 = (f10>0.f)?f10:0.01f*f10; f11 = (f11>0.f)?f11:0.01f*f11;
    f12 = (f12>0.f)?f12:0.01f*f12; f13 = (f13>0.f)?f13:0.01f*f13;
    if (writef){
      *reinterpret_cast<unsigned*>(ebuf + edge*DD + q*4)      = pk4f8(f00,f01,f02,f03);
      *reinterpret_cast<unsigned*>(ebuf + edge*DD + 16 + q*4) = pk4f8(f10,f11,f12,f13);
    }
    float l = f00*alo.x + f01*alo.y + f02*alo.z + f03*alo.w
            + f10*ahi.x + f11*ahi.y + f12*ahi.z + f13*ahi.w;
    l += __shfl_xor(l, 16, 64);
    l += __shfl_xor(l, 32, 64);
    if (lane < 16){
      float lc = fminf(fmaxf(l, -15.f), 10.5f);
      lbuf[tbase + lane] = f2h(__expf(lc));   // max-free softmax weight
    }
    sd_c = sd_n; b_c = b_n;
    uA0_c=uA0_n; uA1_c=uA1_n; uB0_c=uB0_n; uB1_c=uB1_n;
  }
}

// per dst node (32 lanes, CSR): g16 = fp16( (sum ex*h16[src]) / (sum ex) )
__global__ __launch_bounds__(256) void k_aggr(
    const unsigned short* __restrict__ h16, const unsigned short* __restrict__ lbuf,
    const int* __restrict__ off, const unsigned* __restrict__ csr_sd,
    unsigned short* __restrict__ g16, int N)
{
  int tid=threadIdx.x;
  int n = blockIdx.x*8 + (tid>>5);
  int c = tid&31;
  if (n>=N) return;
  int o0 = off[n], o1 = off[n+1];
  float num=0.f, den=0.f;
  for (int i=o0;i<o1;i++){
    float ex = h2f(lbuf[i]);
    unsigned s = csr_sd[i] & 0xFFFFu;
    num = fmaf(ex, h2f(h16[(long)s*DD+c]), num);
    den += ex;
  }
  g16[(long)n*DD+c] = f2h((den>0.f) ? num/den : 0.f);
}

// fused proj + next-layer nodeAB: h16 = relu(g@Wnd); hA16 = h@WA; hB16 = h@WB
__global__ __launch_bounds__(256) void k_pnAB(
    const unsigned short* __restrict__ g16, const float* __restrict__ Wnd,
    const float* __restrict__ WA, const float* __restrict__ WB,
    unsigned short* __restrict__ h16,
    unsigned short* __restrict__ hA16, unsigned short* __restrict__ hB16, int N)
{
  __shared__ float gl[8][DD];
  __shared__ float tl[8][DD];
  int tid = threadIdx.x;
  int ln = tid>>5, c = tid&31;
  int n = blockIdx.x*8 + ln;
  gl[ln][c] = (n<N)? h2f(g16[(long)n*DD+c]) : 0.f;
  __syncthreads();
  float t=0.f;
  #pragma unroll
  for (int k=0;k<DD;k++) t = fmaf(gl[ln][k], Wnd[k*DD+c], t);
  t = fmaxf(t, 0.f);
  tl[ln][c] = t;
  __syncthreads();
  float a=0.f,b=0.f;
  #pragma unroll
  for (int k=0;k<DD;k++){
    float v = tl[ln][k];
    a = fmaf(v, WA[k*DD+c], a);
    b = fmaf(v, WB[k*DD+c], b);
  }
  if (n<N){
    h16[(long)n*DD+c]=f2h(t);
    hA16[(long)n*DD+c]=f2h(a);
    hB16[(long)n*DD+c]=f2h(b);
  }
}

// final proj: h(fp32) = relu(g @ Wnode)
__global__ __launch_bounds__(256) void k_proj(
    const unsigned short* __restrict__ g16, const float* __restrict__ W,
    float* __restrict__ h, int N)
{
  __shared__ float gl[8][DD];
  int tid = threadIdx.x;
  int ln = tid>>5, c = tid&31;
  int n = blockIdx.x*8 + ln;
  gl[ln][c] = (n<N)? h2f(g16[(long)n*DD+c]) : 0.f;
  __syncthreads();
  float a=0.f;
  #pragma unroll
  for (int k=0;k<DD;k++) a = fmaf(gl[ln][k], W[k*DD+c], a);
  if (n<N) h[(long)n*DD+c] = fmaxf(a, 0.f);
}

__global__ void k_keys(const float* __restrict__ h, unsigned long long* __restrict__ keys, int N){
  int n = blockIdx.x*blockDim.x + threadIdx.x;
  if (n>=N) return;
  const float4* p = reinterpret_cast<const float4*>(h + (long)n*DD);
  float m = -1e38f;
  #pragma unroll
  for (int j=0;j<8;j++){
    float4 v = p[j];
    m = fmaxf(m, fmaxf(fmaxf(v.x,v.y), fmaxf(v.z,v.w)));
  }
  keys[n] = ((unsigned long long)encf(m)<<32) | (unsigned)(~(unsigned)n);
}

// parallel top-8: per-thread register top-8 + 8-round block tournament (keys unique)
__global__ __launch_bounds__(256) void k_ptop(const unsigned long long* __restrict__ keys, int N,
                                              unsigned long long* __restrict__ outk){
  __shared__ unsigned long long red[256];
  int tid = threadIdx.x, b = blockIdx.x, nb = gridDim.x;
  int chunk = (N + nb - 1) / nb;
  int base = b*chunk, end = base+chunk; if (end>N) end=N;
  unsigned long long loc[TOPK];
  #pragma unroll
  for (int i=0;i<TOPK;i++) loc[i]=0ull;
  for (int i=base+tid; i<end; i+=256){
    unsigned long long k = keys[i];
    if (k > loc[TOPK-1]){
      int j = TOPK-1;
      while (j>0 && loc[j-1]<k){ loc[j]=loc[j-1]; j--; }
      loc[j]=k;
    }
  }
  for (int r=0; r<TOPK; r++){
    red[tid] = loc[0];
    __syncthreads();
    for (int s=128; s>0; s>>=1){
      if (tid<s && red[tid+s]>red[tid]) red[tid]=red[tid+s];
      __syncthreads();
    }
    unsigned long long w = red[0];
    if (tid==0) outk[b*TOPK + r] = w;
    if (loc[0]==w){
      #pragma unroll
      for (int j=0;j<TOPK-1;j++) loc[j]=loc[j+1];
      loc[TOPK-1]=0ull;
    }
    __syncthreads();
  }
}

__global__ __launch_bounds__(256) void k_head(
    const float* __restrict__ h, const unsigned long long* __restrict__ sel,
    const float* __restrict__ Wlin, const float* __restrict__ blin,
    const float* __restrict__ W1, const float* __restrict__ b1,
    const float* __restrict__ W2, const float* __restrict__ b2,
    const float* __restrict__ Wc, const float* __restrict__ bc,
    float* __restrict__ out, int N)
{
  __shared__ float xs[TOPK][DD];
  __shared__ float y1[DD], y2[DD], y3[DD];
  int tid=threadIdx.x;
  int r=tid>>5, c=tid&31;
  unsigned node = ~(unsigned)(sel[r] & 0xFFFFFFFFull);
  if (node >= (unsigned)N) node = 0;
  xs[r][c] = h[(long)node*DD + c];
  __syncthreads();
  if (tid<TOPK){
    for (int i=1;i<DD;i++){
      float v=xs[tid][i]; int j=i-1;
      while (j>=0 && xs[tid][j]>v){ xs[tid][j+1]=xs[tid][j]; j--; }
      xs[tid][j+1]=v;
    }
  }
  __syncthreads();
  if (tid<DD){
    float a=blin[tid];
    for (int i=0;i<TOPK*DD;i++) a = fmaf(xs[i>>5][i&31], Wlin[i*DD+tid], a);
    y1[tid] = a>0.f? a : 0.f;
  }
  __syncthreads();
  if (tid<DD){
    float a=b1[tid];
    #pragma unroll
    for (int i=0;i<DD;i++) a = fmaf(y1[i], W1[i*DD+tid], a);
    y2[tid] = a>0.f? a : 0.f;
  }
  __syncthreads();
  if (tid<DD){
    float a=b2[tid];
    #pragma unroll
    for (int i=0;i<DD;i++) a = fmaf(y2[i], W2[i*DD+tid], a);
    y3[tid] = a>0.f? a : 0.f;
  }
  __syncthreads();
  if (tid<2){
    float a=bc[tid];
    #pragma unroll
    for (int i=0;i<DD;i++) a = fmaf(y3[i], Wc[i*2+tid], a);
    out[tid] = a;                       // fp32 output
  }
}

extern "C" void kernel_launch(void* const* d_in, const int* in_sizes, int n_in,
                              void* d_out, int out_size, void* d_ws, size_t ws_size,
                              hipStream_t stream) {
  const int N = in_sizes[0];
  const int E = in_sizes[1];
  const float* tok_emb   = (const float*)d_in[4];
  const float* e_tok_emb = (const float*)d_in[5];
  const float* W_ni  = (const float*)d_in[6];
  const float* W_nj  = (const float*)d_in[7];
  const float* W_fij = (const float*)d_in[8];
  const float* b_e   = (const float*)d_in[9];
  const float* attn  = (const float*)d_in[10];
  const float* W_nd  = (const float*)d_in[11];

  char* p = (char*)d_ws;
  auto alloc = [&](size_t bytes)->char* {
    char* r = p; p += (bytes + 255) & ~(size_t)255; return r;
  };
  // ~80 MB total (ebuf now fp8)
  int* iflag = (int*)alloc(256);
  unsigned long long* sel = (unsigned long long*)alloc(256);
  unsigned long long* cand = (unsigned long long*)alloc(256*TOPK*8);
  int* csroff = (int*)alloc((size_t)(N+1)*4);
  unsigned* csr_sd = (unsigned*)alloc((size_t)(E+16)*4);
  float* h = (float*)alloc((size_t)N*DD*4);                     // fp32, final only
  unsigned short* g16  = (unsigned short*)alloc((size_t)N*DD*2);
  unsigned short* lbuf = (unsigned short*)alloc((size_t)(E+16)*2);
  unsigned short* h16  = (unsigned short*)alloc((size_t)N*DD*2);
  unsigned short* hA16 = (unsigned short*)alloc((size_t)N*DD*2);
  unsigned short* hB16 = (unsigned short*)alloc((size_t)N*DD*2);
  unsigned char* ebuf = (unsigned char*)alloc((size_t)(E+16)*DD);
  int* cnt    = (int*)hA16;                       // alias: dead until nodeAB
  int* cursor = (int*)hB16;                       // alias: dead until nodeAB
  uint2* sde8 = (uint2*)h;                        // alias: spans h+g16+lbuf (12.8 MB)
  unsigned long long* keys = (unsigned long long*)lbuf;  // alias: lbuf dead after last aggr

  hipLaunchKernelGGL(k_detect, dim3(1), dim3(64), 0, stream, (const int*)d_in[2], iflag);
  hipLaunchKernelGGL(k_zero, dim3((N+255)/256), dim3(256), 0, stream, cnt, cursor, N);
  {
    long total = (long)N*8 + E;
    hipLaunchKernelGGL(k_init, dim3((int)((total+255)/256)), dim3(256), 0, stream,
                       d_in[0], d_in[3], tok_emb, h16, cnt, iflag, N, E);
  }
  hipLaunchKernelGGL(k_scan, dim3(1), dim3(1024), 0, stream, cnt, csroff, N, E);
  hipLaunchKernelGGL(k_scatter, dim3((E+255)/256), dim3(256), 0, stream,
                     d_in[2], d_in[3], csroff, cursor, sde8, iflag, E);
  hipLaunchKernelGGL(k_fill, dim3((int)(((long)E*2+255)/256)), dim3(256), 0, stream,
                     sde8, d_in[1], e_tok_emb, csr_sd, ebuf, iflag, E);

  int nb_node = (N+7)/8;
  int ntiles = (E+15)/16;
  hipLaunchKernelGGL(k_nodeAB, dim3(nb_node), dim3(256), 0, stream,
                     h16, W_ni, W_nj, hA16, hB16, N);
  for (int l=0; l<NLAYERS; l++){
    const float* Wf  = W_fij + (size_t)l*DD*DD;
    const float* bl  = b_e   + (size_t)l*DD;
    const float* at  = attn  + (size_t)l*DD;
    const float* Wnd = W_nd  + (size_t)l*DD*DD;
    hipLaunchKernelGGL(k_edge, dim3(2048), dim3(256), 0, stream,
                       ebuf, hA16, hB16, csr_sd, Wf, bl, at, lbuf, ntiles,
                       (l < NLAYERS-1) ? 1 : 0);
    hipLaunchKernelGGL(k_aggr, dim3(nb_node), dim3(256), 0, stream,
                       h16, lbuf, csroff, csr_sd, g16, N);
    if (l < NLAYERS-1){
      const float* WnA = W_ni + (size_t)(l+1)*DD*DD;
      const float* WnB = W_nj + (size_t)(l+1)*DD*DD;
      hipLaunchKernelGGL(k_pnAB, dim3(nb_node), dim3(256), 0, stream,
                         g16, Wnd, WnA, WnB, h16, hA16, hB16, N);
    } else {
      hipLaunchKernelGGL(k_proj, dim3(nb_node), dim3(256), 0, stream,
                         g16, Wnd, h, N);
    }
  }

  hipLaunchKernelGGL(k_keys, dim3((N+255)/256), dim3(256), 0, stream, h, keys, N);
  hipLaunchKernelGGL(k_ptop, dim3(256), dim3(256), 0, stream, keys, N, cand);
  hipLaunchKernelGGL(k_ptop, dim3(1), dim3(256), 0, stream, cand, 256*TOPK, sel);
  hipLaunchKernelGGL(k_head, dim3(1), dim3(256), 0, stream,
                     h, sel,
                     (const float*)d_in[12], (const float*)d_in[13],
                     (const float*)d_in[14], (const float*)d_in[15],
                     (const float*)d_in[16], (const float*)d_in[17],
                     (const float*)d_in[18], (const float*)d_in[19],
                     (float*)d_out, N);
}

// Round 19
// 1421.196 us; speedup vs baseline: 1.0168x; 1.0168x over previous
//
#include <hip/hip_runtime.h>
#include <hip/hip_fp16.h>

#define DD 32
#define NLAYERS 8
#define TOPK 8

typedef _Float16 half8 __attribute__((ext_vector_type(8)));
typedef float f32x4 __attribute__((ext_vector_type(4)));

__device__ __forceinline__ unsigned encf(float x){ unsigned u=__float_as_uint(x); return (u&0x80000000u)? ~u : (u|0x80000000u); }
__device__ __forceinline__ unsigned short f2h(float f){ return __half_as_ushort(__float2half(f)); }
__device__ __forceinline__ float h2f(unsigned short u){ return __half2float(__ushort_as_half(u)); }
__device__ __forceinline__ float4 up4(uint2 u){
  float4 r;
  r.x=h2f((unsigned short)(u.x&0xFFFFu)); r.y=h2f((unsigned short)(u.x>>16));
  r.z=h2f((unsigned short)(u.y&0xFFFFu)); r.w=h2f((unsigned short)(u.y>>16));
  return r;
}
union HU { uint2 u; half8 h; };   // b-fragment reinterpret (8 fp16 = 4 VGPRs... 2x uint2)
union HU4 { uint4 u; half8 h; };
__device__ __forceinline__ int gidx(const void* p, long i, int i64){
  return i64 ? (int)((const long long*)p)[i] : ((const int*)p)[i];
}

__global__ void k_detect(const int* __restrict__ srcw, int* __restrict__ iflag){
  if (threadIdx.x==0 && blockIdx.x==0){
    int allz = 1;
    for (int k=1;k<32;k+=2) if (srcw[k]!=0) allz = 0;
    *iflag = allz;
  }
}

__global__ void k_zero(int* cnt, int* cursor, int N){
  int n = blockIdx.x*blockDim.x + threadIdx.x;
  if (n<N){ cnt[n]=0; cursor[n]=0; }
}

// h16 = fp16(relu(tok_emb[h_tok])) ; in-degree histogram
__global__ void k_init(const void* __restrict__ h_tok, const void* __restrict__ dstv,
                       const float* __restrict__ tok_emb,
                       unsigned short* __restrict__ h16, int* __restrict__ cnt,
                       const int* __restrict__ iflag, int N, int E)
{
  int i64 = *iflag;
  long idx = (long)blockIdx.x*blockDim.x + threadIdx.x;
  if (idx < (long)N*8){
    int n=(int)(idx>>3), q=(int)(idx&7);
    int t = gidx(h_tok, n, i64);
    float4 v = reinterpret_cast<const float4*>(tok_emb)[t*8+q];
    uint2 o;
    o.x = (unsigned)f2h(fmaxf(v.x,0.f)) | ((unsigned)f2h(fmaxf(v.y,0.f))<<16);
    o.y = (unsigned)f2h(fmaxf(v.z,0.f)) | ((unsigned)f2h(fmaxf(v.w,0.f))<<16);
    reinterpret_cast<uint2*>(h16)[(long)n*8+q] = o;
    return;
  }
  idx -= (long)N*8;
  if (idx < E){
    atomicAdd(&cnt[gidx(dstv, idx, i64)], 1);
  }
}

// single-block exclusive scan of in-degrees -> csr_off (wave shuffle-scan)
__global__ __launch_bounds__(1024) void k_scan(const int* __restrict__ cnt, int* __restrict__ off,
                                               int N, int E){
  __shared__ int wsum[16];
  __shared__ int carry_s;
  int tid = threadIdx.x;
  int lane = tid & 63, w = tid >> 6;
  if (tid==0) carry_s = 0;
  __syncthreads();
  for (int base=0; base<N; base+=1024){
    int v = (base+tid<N)? cnt[base+tid] : 0;
    int x = v;
    #pragma unroll
    for (int d=1; d<64; d<<=1){
      int t = __shfl_up(x, d, 64);
      if (lane>=d) x += t;
    }
    if (lane==63) wsum[w] = x;
    __syncthreads();
    if (w==0 && lane<16){
      int y = wsum[lane];
      #pragma unroll
      for (int d=1; d<16; d<<=1){
        int t = __shfl_up(y, d, 64);
        if (lane>=d) y += t;
      }
      wsum[lane] = y;
    }
    __syncthreads();
    int cl = carry_s;
    int wb = (w>0)? wsum[w-1] : 0;
    int tot = wsum[15];
    if (base+tid<N) off[base+tid] = cl + x + wb - v;
    __syncthreads();
    if (tid==0) carry_s = cl + tot;
    __syncthreads();
  }
  if (tid==0) off[N] = E;
}

// CSR positions: ONE 8-B scatter per edge (sd + edge id in a single uint2)
__global__ void k_scatter(const void* __restrict__ srcv, const void* __restrict__ dstv,
                          const int* __restrict__ off, int* __restrict__ cursor,
                          uint2* __restrict__ sde8,
                          const int* __restrict__ iflag, int E){
  int i64 = *iflag;
  int e = blockIdx.x*blockDim.x + threadIdx.x;
  if (e>=E) return;
  int d = gidx(dstv, e, i64), s = gidx(srcv, e, i64);
  int pos = off[d] + atomicAdd(&cursor[d],1);
  uint2 r; r.x = ((unsigned)d<<16) | (unsigned)s; r.y = (unsigned)e;
  sde8[pos] = r;
}

// stream sde8: emit csr_sd sequentially + fill ebuf (fp16) from L1-resident e_emb table
__global__ void k_fill(const uint2* __restrict__ sde8, const void* __restrict__ e_tok,
                       const float* __restrict__ e_emb,
                       unsigned* __restrict__ csr_sd, unsigned short* __restrict__ ebuf,
                       const int* __restrict__ iflag, int E){
  int i64 = *iflag;
  long idx = (long)blockIdx.x*blockDim.x + threadIdx.x;
  if (idx >= (long)E*4) return;
  int pos = (int)(idx>>2), j = (int)(idx&3);
  uint2 r = sde8[pos];
  if (j==0) csr_sd[pos] = r.x;
  int t = gidx(e_tok, (int)r.y, i64);
  const float4* sp = reinterpret_cast<const float4*>(e_emb + t*DD) + j*2;
  float4 x = sp[0], y = sp[1];
  uint4 ov;
  ov.x = (unsigned)f2h(x.x) | ((unsigned)f2h(x.y)<<16);
  ov.y = (unsigned)f2h(x.z) | ((unsigned)f2h(x.w)<<16);
  ov.z = (unsigned)f2h(y.x) | ((unsigned)f2h(y.y)<<16);
  ov.w = (unsigned)f2h(y.z) | ((unsigned)f2h(y.w)<<16);
  reinterpret_cast<uint4*>(ebuf)[(long)pos*4+j] = ov;
}

// hA16=h16@Wni, hB16=h16@Wnj   (first layer only)
__global__ __launch_bounds__(256) void k_nodeAB(
    const unsigned short* __restrict__ h16,
    const float* __restrict__ WA, const float* __restrict__ WB,
    unsigned short* __restrict__ hA16, unsigned short* __restrict__ hB16, int N)
{
  __shared__ float hl[8][DD];
  int tid = threadIdx.x;
  int ln = tid>>5, c = tid&31;
  int n = blockIdx.x*8 + ln;
  hl[ln][c] = (n<N)? h2f(h16[(long)n*DD+c]) : 0.f;
  __syncthreads();
  float a=0.f,b=0.f;
  #pragma unroll
  for (int k=0;k<DD;k++){
    float v = hl[ln][k];
    a = fmaf(v, WA[k*DD+c], a);
    b = fmaf(v, WB[k*DD+c], b);
  }
  if (n<N){ hA16[(long)n*DD+c]=f2h(a); hB16[(long)n*DD+c]=f2h(b); }
}

// MFMA fp16 edge kernel, SOFTWARE-PIPELINED depth 2: one wave = 16 edges.
// D[m][n=edge]=Wf^T·e^T; f=leaky(D+hA[src]+hB[dst]+b); ebuf<-f; lbuf=exp(f·attn)
__global__ __launch_bounds__(256) void k_edge(
    unsigned short* __restrict__ ebuf,
    const unsigned short* __restrict__ hA16, const unsigned short* __restrict__ hB16,
    const unsigned* __restrict__ csr_sd,
    const float* __restrict__ Wf, const float* __restrict__ bvec,
    const float* __restrict__ attn,
    unsigned short* __restrict__ lbuf, int ntiles, int writef)
{
  int lane = threadIdx.x & 63;
  int wid = (blockIdx.x*256 + threadIdx.x) >> 6;
  int nw  = (gridDim.x*256) >> 6;
  int m = lane & 15, q = lane >> 4;
  half8 a0, a1;
  #pragma unroll
  for (int j=0;j<8;j++){
    a0[j] = (_Float16)Wf[(q*8+j)*DD + m];
    a1[j] = (_Float16)Wf[(q*8+j)*DD + 16 + m];
  }
  float4 blo = *reinterpret_cast<const float4*>(bvec + q*4);
  float4 bhi = *reinterpret_cast<const float4*>(bvec + 16 + q*4);
  float4 alo = *reinterpret_cast<const float4*>(attn + q*4);
  float4 ahi = *reinterpret_cast<const float4*>(attn + 16 + q*4);
  f32x4 zero = {0.f,0.f,0.f,0.f};
  // depth-2 preamble: tile0 = fully loaded; tile1 = sd+b loaded
  HU4 b0; b0.u = make_uint4(0,0,0,0);
  HU4 b1; b1.u = make_uint4(0,0,0,0);
  unsigned sd0 = 0, sd1 = 0;
  uint2 gA0_0={0,0}, gA1_0={0,0}, gB0_0={0,0}, gB1_0={0,0};
  if (wid < ntiles){
    long e0 = (long)wid*16 + m;
    sd0 = csr_sd[e0];
    b0.u = *reinterpret_cast<const uint4*>(ebuf + e0*DD + q*8);
    unsigned s = sd0 & 0xFFFFu, d = sd0 >> 16;
    const uint2* pA = reinterpret_cast<const uint2*>(hA16 + (long)s*DD);
    const uint2* pB = reinterpret_cast<const uint2*>(hB16 + (long)d*DD);
    gA0_0=pA[q]; gA1_0=pA[4+q]; gB0_0=pB[q]; gB1_0=pB[4+q];
  }
  if (wid + nw < ntiles){
    long e1 = (long)(wid+nw)*16 + m;
    sd1 = csr_sd[e1];
    b1.u = *reinterpret_cast<const uint4*>(ebuf + e1*DD + q*8);
  }
  for (int t = wid; t < ntiles; t += nw){
    int t1 = t + nw, t2 = t + 2*nw;
    // 1) issue sd/b for tile t+2nw (fully independent)
    unsigned sd2 = 0; HU4 b2; b2.u = make_uint4(0,0,0,0);
    if (t2 < ntiles){
      long e2 = (long)t2*16 + m;
      sd2 = csr_sd[e2];
      b2.u = *reinterpret_cast<const uint4*>(ebuf + e2*DD + q*8);
    }
    // 2) issue gathers for tile t+nw (dep: sd1, resident since last iteration)
    uint2 gA0_1={0,0}, gA1_1={0,0}, gB0_1={0,0}, gB1_1={0,0};
    if (t1 < ntiles){
      unsigned s = sd1 & 0xFFFFu, d = sd1 >> 16;
      const uint2* pA = reinterpret_cast<const uint2*>(hA16 + (long)s*DD);
      const uint2* pB = reinterpret_cast<const uint2*>(hB16 + (long)d*DD);
      gA0_1=pA[q]; gA1_1=pA[4+q]; gB0_1=pB[q]; gB1_1=pB[4+q];
    }
    // 3) MFMA on current tile (b0 resident)
    f32x4 d0 = __builtin_amdgcn_mfma_f32_16x16x32_f16(a0, b0.h, zero, 0,0,0);
    f32x4 d1 = __builtin_amdgcn_mfma_f32_16x16x32_f16(a1, b0.h, zero, 0,0,0);
    // 4) epilogue with current gathers (issued a full iteration ago)
    long tbase = (long)t*16;
    long edge = tbase + m;
    float4 A0 = up4(gA0_0), A1 = up4(gA1_0);
    float4 B0 = up4(gB0_0), B1 = up4(gB1_0);
    float f00 = d0[0]+A0.x+B0.x+blo.x, f01 = d0[1]+A0.y+B0.y+blo.y;
    float f02 = d0[2]+A0.z+B0.z+blo.z, f03 = d0[3]+A0.w+B0.w+blo.w;
    float f10 = d1[0]+A1.x+B1.x+bhi.x, f11 = d1[1]+A1.y+B1.y+bhi.y;
    float f12 = d1[2]+A1.z+B1.z+bhi.z, f13 = d1[3]+A1.w+B1.w+bhi.w;
    f00 = (f00>0.f)?f00:0.01f*f00; f01 = (f01>0.f)?f01:0.01f*f01;
    f02 = (f02>0.f)?f02:0.01f*f02; f03 = (f03>0.f)?f03:0.01f*f03;
    f10 = (f10>0.f)?f10:0.01f*f10; f11 = (f11>0.f)?f11:0.01f*f11;
    f12 = (f12>0.f)?f12:0.01f*f12; f13 = (f13>0.f)?f13:0.01f*f13;
    if (writef){
      uint2 w0, w1;
      w0.x = (unsigned)f2h(f00) | ((unsigned)f2h(f01)<<16);
      w0.y = (unsigned)f2h(f02) | ((unsigned)f2h(f03)<<16);
      w1.x = (unsigned)f2h(f10) | ((unsigned)f2h(f11)<<16);
      w1.y = (unsigned)f2h(f12) | ((unsigned)f2h(f13)<<16);
      *reinterpret_cast<uint2*>(ebuf + edge*DD + q*4) = w0;
      *reinterpret_cast<uint2*>(ebuf + edge*DD + 16 + q*4) = w1;
    }
    float l = f00*alo.x + f01*alo.y + f02*alo.z + f03*alo.w
            + f10*ahi.x + f11*ahi.y + f12*ahi.z + f13*ahi.w;
    l += __shfl_xor(l, 16, 64);
    l += __shfl_xor(l, 32, 64);
    if (lane < 16){
      float lc = fminf(fmaxf(l, -15.f), 10.5f);
      lbuf[tbase + lane] = f2h(__expf(lc));   // max-free softmax weight
    }
    // rotate pipeline
    sd0 = sd1; b0 = b1;
    gA0_0=gA0_1; gA1_0=gA1_1; gB0_0=gB0_1; gB1_0=gB1_1;
    sd1 = sd2; b1 = b2;
  }
}

// per dst node (32 lanes, CSR): g16 = fp16( (sum ex*h16[src]) / (sum ex) )
__global__ __launch_bounds__(256) void k_aggr(
    const unsigned short* __restrict__ h16, const unsigned short* __restrict__ lbuf,
    const int* __restrict__ off, const unsigned* __restrict__ csr_sd,
    unsigned short* __restrict__ g16, int N)
{
  int tid=threadIdx.x;
  int n = blockIdx.x*8 + (tid>>5);
  int c = tid&31;
  if (n>=N) return;
  int o0 = off[n], o1 = off[n+1];
  float num=0.f, den=0.f;
  for (int i=o0;i<o1;i++){
    float ex = h2f(lbuf[i]);
    unsigned s = csr_sd[i] & 0xFFFFu;
    num = fmaf(ex, h2f(h16[(long)s*DD+c]), num);
    den += ex;
  }
  g16[(long)n*DD+c] = f2h((den>0.f) ? num/den : 0.f);
}

// fused proj + next-layer nodeAB: h16 = relu(g@Wnd); hA16 = h@WA; hB16 = h@WB
__global__ __launch_bounds__(256) void k_pnAB(
    const unsigned short* __restrict__ g16, const float* __restrict__ Wnd,
    const float* __restrict__ WA, const float* __restrict__ WB,
    unsigned short* __restrict__ h16,
    unsigned short* __restrict__ hA16, unsigned short* __restrict__ hB16, int N)
{
  __shared__ float gl[8][DD];
  __shared__ float tl[8][DD];
  int tid = threadIdx.x;
  int ln = tid>>5, c = tid&31;
  int n = blockIdx.x*8 + ln;
  gl[ln][c] = (n<N)? h2f(g16[(long)n*DD+c]) : 0.f;
  __syncthreads();
  float t=0.f;
  #pragma unroll
  for (int k=0;k<DD;k++) t = fmaf(gl[ln][k], Wnd[k*DD+c], t);
  t = fmaxf(t, 0.f);
  tl[ln][c] = t;
  __syncthreads();
  float a=0.f,b=0.f;
  #pragma unroll
  for (int k=0;k<DD;k++){
    float v = tl[ln][k];
    a = fmaf(v, WA[k*DD+c], a);
    b = fmaf(v, WB[k*DD+c], b);
  }
  if (n<N){
    h16[(long)n*DD+c]=f2h(t);
    hA16[(long)n*DD+c]=f2h(a);
    hB16[(long)n*DD+c]=f2h(b);
  }
}

// final proj: h(fp32) = relu(g @ Wnode)
__global__ __launch_bounds__(256) void k_proj(
    const unsigned short* __restrict__ g16, const float* __restrict__ W,
    float* __restrict__ h, int N)
{
  __shared__ float gl[8][DD];
  int tid = threadIdx.x;
  int ln = tid>>5, c = tid&31;
  int n = blockIdx.x*8 + ln;
  gl[ln][c] = (n<N)? h2f(g16[(long)n*DD+c]) : 0.f;
  __syncthreads();
  float a=0.f;
  #pragma unroll
  for (int k=0;k<DD;k++) a = fmaf(gl[ln][k], W[k*DD+c], a);
  if (n<N) h[(long)n*DD+c] = fmaxf(a, 0.f);
}

__global__ void k_keys(const float* __restrict__ h, unsigned long long* __restrict__ keys, int N){
  int n = blockIdx.x*blockDim.x + threadIdx.x;
  if (n>=N) return;
  const float4* p = reinterpret_cast<const float4*>(h + (long)n*DD);
  float m = -1e38f;
  #pragma unroll
  for (int j=0;j<8;j++){
    float4 v = p[j];
    m = fmaxf(m, fmaxf(fmaxf(v.x,v.y), fmaxf(v.z,v.w)));
  }
  keys[n] = ((unsigned long long)encf(m)<<32) | (unsigned)(~(unsigned)n);
}

// parallel top-8: per-thread register top-8 + 8-round block tournament (keys unique)
__global__ __launch_bounds__(256) void k_ptop(const unsigned long long* __restrict__ keys, int N,
                                              unsigned long long* __restrict__ outk){
  __shared__ unsigned long long red[256];
  int tid = threadIdx.x, b = blockIdx.x, nb = gridDim.x;
  int chunk = (N + nb - 1) / nb;
  int base = b*chunk, end = base+chunk; if (end>N) end=N;
  unsigned long long loc[TOPK];
  #pragma unroll
  for (int i=0;i<TOPK;i++) loc[i]=0ull;
  for (int i=base+tid; i<end; i+=256){
    unsigned long long k = keys[i];
    if (k > loc[TOPK-1]){
      int j = TOPK-1;
      while (j>0 && loc[j-1]<k){ loc[j]=loc[j-1]; j--; }
      loc[j]=k;
    }
  }
  for (int r=0; r<TOPK; r++){
    red[tid] = loc[0];
    __syncthreads();
    for (int s=128; s>0; s>>=1){
      if (tid<s && red[tid+s]>red[tid]) red[tid]=red[tid+s];
      __syncthreads();
    }
    unsigned long long w = red[0];
    if (tid==0) outk[b*TOPK + r] = w;
    if (loc[0]==w){
      #pragma unroll
      for (int j=0;j<TOPK-1;j++) loc[j]=loc[j+1];
      loc[TOPK-1]=0ull;
    }
    __syncthreads();
  }
}

__global__ __launch_bounds__(256) void k_head(
    const float* __restrict__ h, const unsigned long long* __restrict__ sel,
    const float* __restrict__ Wlin, const float* __restrict__ blin,
    const float* __restrict__ W1, const float* __restrict__ b1,
    const float* __restrict__ W2, const float* __restrict__ b2,
    const float* __restrict__ Wc, const float* __restrict__ bc,
    float* __restrict__ out, int N)
{
  __shared__ float xs[TOPK][DD];
  __shared__ float y1[DD], y2[DD], y3[DD];
  int tid=threadIdx.x;
  int r=tid>>5, c=tid&31;
  unsigned node = ~(unsigned)(sel[r] & 0xFFFFFFFFull);
  if (node >= (unsigned)N) node = 0;
  xs[r][c] = h[(long)node*DD + c];
  __syncthreads();
  if (tid<TOPK){
    for (int i=1;i<DD;i++){
      float v=xs[tid][i]; int j=i-1;
      while (j>=0 && xs[tid][j]>v){ xs[tid][j+1]=xs[tid][j]; j--; }
      xs[tid][j+1]=v;
    }
  }
  __syncthreads();
  if (tid<DD){
    float a=blin[tid];
    for (int i=0;i<TOPK*DD;i++) a = fmaf(xs[i>>5][i&31], Wlin[i*DD+tid], a);
    y1[tid] = a>0.f? a : 0.f;
  }
  __syncthreads();
  if (tid<DD){
    float a=b1[tid];
    #pragma unroll
    for (int i=0;i<DD;i++) a = fmaf(y1[i], W1[i*DD+tid], a);
    y2[tid] = a>0.f? a : 0.f;
  }
  __syncthreads();
  if (tid<DD){
    float a=b2[tid];
    #pragma unroll
    for (int i=0;i<DD;i++) a = fmaf(y2[i], W2[i*DD+tid], a);
    y3[tid] = a>0.f? a : 0.f;
  }
  __syncthreads();
  if (tid<2){
    float a=bc[tid];
    #pragma unroll
    for (int i=0;i<DD;i++) a = fmaf(y3[i], Wc[i*2+tid], a);
    out[tid] = a;                       // fp32 output
  }
}

extern "C" void kernel_launch(void* const* d_in, const int* in_sizes, int n_in,
                              void* d_out, int out_size, void* d_ws, size_t ws_size,
                              hipStream_t stream) {
  const int N = in_sizes[0];
  const int E = in_sizes[1];
  const float* tok_emb   = (const float*)d_in[4];
  const float* e_tok_emb = (const float*)d_in[5];
  const float* W_ni  = (const float*)d_in[6];
  const float* W_nj  = (const float*)d_in[7];
  const float* W_fij = (const float*)d_in[8];
  const float* b_e   = (const float*)d_in[9];
  const float* attn  = (const float*)d_in[10];
  const float* W_nd  = (const float*)d_in[11];

  char* p = (char*)d_ws;
  auto alloc = [&](size_t bytes)->char* {
    char* r = p; p += (bytes + 255) & ~(size_t)255; return r;
  };
  // ~131.5 MB total (sde8 aliases h+g16+lbuf, all dead at setup)
  int* iflag = (int*)alloc(256);
  unsigned long long* sel = (unsigned long long*)alloc(256);
  unsigned long long* cand = (unsigned long long*)alloc(256*TOPK*8);
  int* csroff = (int*)alloc((size_t)(N+1)*4);
  unsigned* csr_sd = (unsigned*)alloc((size_t)(E+32)*4);
  float* h = (float*)alloc((size_t)N*DD*4);                     // fp32, final only
  unsigned short* g16  = (unsigned short*)alloc((size_t)N*DD*2);
  unsigned short* lbuf = (unsigned short*)alloc((size_t)(E+32)*2);
  unsigned short* h16  = (unsigned short*)alloc((size_t)N*DD*2);
  unsigned short* hA16 = (unsigned short*)alloc((size_t)N*DD*2);
  unsigned short* hB16 = (unsigned short*)alloc((size_t)N*DD*2);
  unsigned short* ebuf = (unsigned short*)alloc((size_t)(E+32)*DD*2);
  int* cnt    = (int*)hA16;                       // alias: dead until nodeAB
  int* cursor = (int*)hB16;                       // alias: dead until nodeAB
  uint2* sde8 = (uint2*)h;                        // alias: spans h+g16+lbuf (12.8 MB)
  unsigned long long* keys = (unsigned long long*)lbuf;  // alias: lbuf dead after last aggr

  hipLaunchKernelGGL(k_detect, dim3(1), dim3(64), 0, stream, (const int*)d_in[2], iflag);
  hipLaunchKernelGGL(k_zero, dim3((N+255)/256), dim3(256), 0, stream, cnt, cursor, N);
  {
    long total = (long)N*8 + E;
    hipLaunchKernelGGL(k_init, dim3((int)((total+255)/256)), dim3(256), 0, stream,
                       d_in[0], d_in[3], tok_emb, h16, cnt, iflag, N, E);
  }
  hipLaunchKernelGGL(k_scan, dim3(1), dim3(1024), 0, stream, cnt, csroff, N, E);
  hipLaunchKernelGGL(k_scatter, dim3((E+255)/256), dim3(256), 0, stream,
                     d_in[2], d_in[3], csroff, cursor, sde8, iflag, E);
  hipLaunchKernelGGL(k_fill, dim3((int)(((long)E*4+255)/256)), dim3(256), 0, stream,
                     sde8, d_in[1], e_tok_emb, csr_sd, ebuf, iflag, E);

  int nb_node = (N+7)/8;
  int ntiles = (E+15)/16;
  hipLaunchKernelGGL(k_nodeAB, dim3(nb_node), dim3(256), 0, stream,
                     h16, W_ni, W_nj, hA16, hB16, N);
  for (int l=0; l<NLAYERS; l++){
    const float* Wf  = W_fij + (size_t)l*DD*DD;
    const float* bl  = b_e   + (size_t)l*DD;
    const float* at  = attn  + (size_t)l*DD;
    const float* Wnd = W_nd  + (size_t)l*DD*DD;
    hipLaunchKernelGGL(k_edge, dim3(2048), dim3(256), 0, stream,
                       ebuf, hA16, hB16, csr_sd, Wf, bl, at, lbuf, ntiles,
                       (l < NLAYERS-1) ? 1 : 0);
    hipLaunchKernelGGL(k_aggr, dim3(nb_node), dim3(256), 0, stream,
                       h16, lbuf, csroff, csr_sd, g16, N);
    if (l < NLAYERS-1){
      const float* WnA = W_ni + (size_t)(l+1)*DD*DD;
      const float* WnB = W_nj + (size_t)(l+1)*DD*DD;
      hipLaunchKernelGGL(k_pnAB, dim3(nb_node), dim3(256), 0, stream,
                         g16, Wnd, WnA, WnB, h16, hA16, hB16, N);
    } else {
      hipLaunchKernelGGL(k_proj, dim3(nb_node), dim3(256), 0, stream,
                         g16, Wnd, h, N);
    }
  }

  hipLaunchKernelGGL(k_keys, dim3((N+255)/256), dim3(256), 0, stream, h, keys, N);
  hipLaunchKernelGGL(k_ptop, dim3(256), dim3(256), 0, stream, keys, N, cand);
  hipLaunchKernelGGL(k_ptop, dim3(1), dim3(256), 0, stream, cand, 256*TOPK, sel);
  hipLaunchKernelGGL(k_head, dim3(1), dim3(256), 0, stream,
                     h, sel,
                     (const float*)d_in[12], (const float*)d_in[13],
                     (const float*)d_in[14], (const float*)d_in[15],
                     (const float*)d_in[16], (const float*)d_in[17],
                     (const float*)d_in[18], (const float*)d_in[19],
                     (float*)d_out, N);
}